// Round 1
// baseline (1661.164 us; speedup 1.0000x reference)
//
#include <hip/hip_runtime.h>

#define NPTS 4096
#define NQ   8192      // B*N
#define DD   64
#define KNN  16
#define KC   8
#define NSEG 16
#define SEGLEN 256     // NPTS/NSEG
#define FPAD 68        // 67 features + 1 zero pad
#define VOFF 1048576   // B*128*N, float offset of v_world in d_out

__device__ inline float leakyf(float x) { return x > 0.f ? x : 0.1f * x; }

template<int K>
__device__ inline void topk_ins(float (&dv)[K], int (&iv)[K], float d, int m) {
  if (d < dv[K-1]) {
    float vd = d; int vi = m;
#pragma unroll
    for (int s = 0; s < K; ++s) {
      if (vd < dv[s]) {
        float td = dv[s]; int ti = iv[s];
        dv[s] = vd; iv[s] = vi; vd = td; vi = ti;
      }
    }
  }
}

// ---------------- prep: transposes + weighted features + norms ----------------
__global__ __launch_bounds__(256) void k_prep(
    const float* __restrict__ xyz1, const float* __restrict__ xyz2,
    const float* __restrict__ pts1, const float* __restrict__ pts2,
    const float* __restrict__ w_xyz_p, const float* __restrict__ w_points_p,
    float* __restrict__ f1, float* __restrict__ f2,
    float* __restrict__ n1, float* __restrict__ n2,
    float* __restrict__ p1t, float* __restrict__ p2t,
    float* __restrict__ x1t, float* __restrict__ x2t)
{
  int gid = blockIdx.x * 256 + threadIdx.x;   // 0..8191
  int b = gid >> 12, n = gid & (NPTS - 1);
  float wx = w_xyz_p[0], wp = w_points_p[0];
  {
    const float* xb = xyz1 + (size_t)b * 3 * NPTS;
    float x = xb[n], y = xb[NPTS + n], z = xb[2 * NPTS + n];
    float nrm2 = fmaf(z, z, fmaf(y, y, x * x));
    float4 xv; xv.x = x; xv.y = y; xv.z = z; xv.w = nrm2;
    *(float4*)&x1t[(size_t)gid * 4] = xv;
    float fx = wx * x, fy = wx * y, fz = wx * z;
    float acc = fmaf(fz, fz, fmaf(fy, fy, fx * fx));
    float* fr = f1 + (size_t)gid * FPAD;
    fr[0] = fx; fr[1] = fy; fr[2] = fz;
    const float* pb = pts1 + (size_t)b * DD * NPTS;
    float* pr = p1t + (size_t)gid * DD;
    for (int c = 0; c < DD; ++c) {
      float v = pb[(size_t)c * NPTS + n];
      pr[c] = v;
      float fv = wp * v;
      fr[3 + c] = fv;
      acc = fmaf(fv, fv, acc);
    }
    fr[67] = 0.f;
    n1[gid] = acc;
  }
  {
    const float* xb = xyz2 + (size_t)b * 3 * NPTS;
    float x = xb[n], y = xb[NPTS + n], z = xb[2 * NPTS + n];
    float nrm2 = fmaf(z, z, fmaf(y, y, x * x));
    float4 xv; xv.x = x; xv.y = y; xv.z = z; xv.w = nrm2;
    *(float4*)&x2t[(size_t)gid * 4] = xv;
    float fx = wx * x, fy = wx * y, fz = wx * z;
    float acc = fmaf(fz, fz, fmaf(fy, fy, fx * fx));
    float* fr = f2 + (size_t)gid * FPAD;
    fr[0] = fx; fr[1] = fy; fr[2] = fz;
    const float* pb = pts2 + (size_t)b * DD * NPTS;
    float* pr = p2t + (size_t)gid * DD;
    for (int c = 0; c < DD; ++c) {
      float v = pb[(size_t)c * NPTS + n];
      pr[c] = v;
      float fv = wp * v;
      fr[3 + c] = fv;
      acc = fmaf(fv, fv, acc);
    }
    fr[67] = 0.f;
    n2[gid] = acc;
  }
}

// ---------------- knn over xyz1 (K=8), partial per segment ----------------
__global__ __launch_bounds__(256) void k_knn3(
    const float* __restrict__ x4, float* __restrict__ pd, int* __restrict__ pi)
{
  __shared__ __align__(16) float4 sc[128];
  int seg = blockIdx.y;
  int Q = blockIdx.x * 256 + threadIdx.x;
  int b = Q >> 12;
  float4 q = *(const float4*)&x4[(size_t)Q * 4];
  float dv[KC]; int iv[KC];
#pragma unroll
  for (int s = 0; s < KC; ++s) { dv[s] = 3.4e38f; iv[s] = 0; }
  int gbase = (b << 12) + seg * SEGLEN;
  for (int ch = 0; ch < SEGLEN / 128; ++ch) {
    __syncthreads();
    if (threadIdx.x < 128)
      sc[threadIdx.x] = *(const float4*)&x4[(size_t)(gbase + ch * 128 + threadIdx.x) * 4];
    __syncthreads();
    int m0 = seg * SEGLEN + ch * 128;
    for (int j = 0; j < 128; ++j) {
      float4 c = sc[j];
      float dot = fmaf(q.z, c.z, fmaf(q.y, c.y, q.x * c.x));
      float d = fmaxf(q.w + c.w - 2.f * dot, 0.f);
      topk_ins<KC>(dv, iv, d, m0 + j);
    }
  }
  float* pdq = pd + ((size_t)Q * NSEG + seg) * 16;
  int* piq = pi + ((size_t)Q * NSEG + seg) * 16;
#pragma unroll
  for (int s = 0; s < KC; ++s) { pdq[s] = dv[s]; piq[s] = iv[s]; }
}

// ---------------- merge K=8 + rigid velocity regression ----------------
__global__ __launch_bounds__(256) void k_rigid(
    const float* __restrict__ pd, const int* __restrict__ pi,
    const float* __restrict__ x4, const float* __restrict__ vel1,
    float* __restrict__ vout)
{
  int Q = blockIdx.x * 256 + threadIdx.x;
  int b = Q >> 12;
  float dv[KC]; int iv[KC];
#pragma unroll
  for (int s = 0; s < KC; ++s) { dv[s] = 3.4e38f; iv[s] = 0; }
  for (int s = 0; s < NSEG; ++s) {
    const float* pdq = pd + ((size_t)Q * NSEG + s) * 16;
    const int* piq = pi + ((size_t)Q * NSEG + s) * 16;
#pragma unroll
    for (int j = 0; j < KC; ++j) topk_ins<KC>(dv, iv, pdq[j], piq[j]);
  }
  int base = b << 12;
  double a00 = 0, a01 = 0, a02 = 0, a11 = 0, a12 = 0, a22 = 0;
  double r0 = 0, r1 = 0, r2 = 0;
#pragma unroll
  for (int t = 0; t < KC; ++t) {
    float4 c = *(const float4*)&x4[(size_t)(base + iv[t]) * 4];
    float nr = sqrtf(c.w);
    float ux = c.x / nr, uy = c.y / nr, uz = c.z / nr;
    float cv = vel1[base + iv[t]];
    double dx = ux, dy = uy, dz = uz, dvv = cv;
    a00 += dx * dx; a01 += dx * dy; a02 += dx * dz;
    a11 += dy * dy; a12 += dy * dz; a22 += dz * dz;
    r0 += dx * dvv; r1 += dy * dvv; r2 += dz * dvv;
  }
  a00 += 1e-6; a11 += 1e-6; a22 += 1e-6;
  double c00 = a11 * a22 - a12 * a12;
  double c01 = a02 * a12 - a01 * a22;
  double c02 = a01 * a12 - a02 * a11;
  double c11 = a00 * a22 - a02 * a02;
  double c12 = a02 * a01 - a00 * a12;
  double c22 = a00 * a11 - a01 * a01;
  double det = a00 * c00 + a01 * c01 + a02 * c02;
  double inv = 1.0 / det;
  vout[(size_t)Q * 3 + 0] = (float)((c00 * r0 + c01 * r1 + c02 * r2) * inv);
  vout[(size_t)Q * 3 + 1] = (float)((c01 * r0 + c11 * r1 + c12 * r2) * inv);
  vout[(size_t)Q * 3 + 2] = (float)((c02 * r0 + c12 * r1 + c22 * r2) * inv);
}

// ---------------- knn over 67-dim features (K=16), partial per segment ----------------
__global__ __launch_bounds__(256) void k_knnf(
    const float* __restrict__ f1, const float* __restrict__ f2,
    const float* __restrict__ n1, const float* __restrict__ n2,
    float* __restrict__ pd, int* __restrict__ pi)
{
  __shared__ __align__(16) float sf[128 * FPAD];
  __shared__ float sn[128];
  int seg = blockIdx.y;
  int Q = blockIdx.x * 256 + threadIdx.x;
  int b = Q >> 12;
  float4 q[17];
#pragma unroll
  for (int c4 = 0; c4 < 17; ++c4)
    q[c4] = *(const float4*)&f1[(size_t)Q * FPAD + c4 * 4];
  float qn = n1[Q];
  float dv[KNN]; int iv[KNN];
#pragma unroll
  for (int s = 0; s < KNN; ++s) { dv[s] = 3.4e38f; iv[s] = 0; }
  for (int ch = 0; ch < SEGLEN / 128; ++ch) {
    int m0 = seg * SEGLEN + ch * 128;
    int gbase = (b << 12) + m0;
    __syncthreads();
    for (int i = threadIdx.x; i < 128 * 17; i += 256) {
      int row = i / 17, c4 = i - row * 17;
      ((float4*)sf)[row * 17 + c4] =
          *(const float4*)&f2[(size_t)(gbase + row) * FPAD + c4 * 4];
    }
    if (threadIdx.x < 128) sn[threadIdx.x] = n2[gbase + threadIdx.x];
    __syncthreads();
    for (int j = 0; j < 128; ++j) {
      const float4* cf = (const float4*)&sf[j * FPAD];
      float dot = 0.f;
#pragma unroll
      for (int c4 = 0; c4 < 17; ++c4) {
        float4 c = cf[c4];
        dot = fmaf(q[c4].x, c.x, dot);
        dot = fmaf(q[c4].y, c.y, dot);
        dot = fmaf(q[c4].z, c.z, dot);
        dot = fmaf(q[c4].w, c.w, dot);
      }
      float d = fmaxf(qn + sn[j] - 2.f * dot, 0.f);
      topk_ins<KNN>(dv, iv, d, m0 + j);
    }
  }
  float* pdq = pd + ((size_t)Q * NSEG + seg) * 16;
  int* piq = pi + ((size_t)Q * NSEG + seg) * 16;
#pragma unroll
  for (int s = 0; s < KNN; ++s) { pdq[s] = dv[s]; piq[s] = iv[s]; }
}

// ---------------- knn over v_world (K=16), partial per segment ----------------
__global__ __launch_bounds__(256) void k_knnv(
    const float* __restrict__ vw, float* __restrict__ pd, int* __restrict__ pi)
{
  __shared__ __align__(16) float4 sc[128];
  int seg = blockIdx.y;
  int Q = blockIdx.x * 256 + threadIdx.x;
  int b = Q >> 12;
  float qx = vw[(size_t)Q * 3], qy = vw[(size_t)Q * 3 + 1], qz = vw[(size_t)Q * 3 + 2];
  float qn = fmaf(qz, qz, fmaf(qy, qy, qx * qx));
  float dv[KNN]; int iv[KNN];
#pragma unroll
  for (int s = 0; s < KNN; ++s) { dv[s] = 3.4e38f; iv[s] = 0; }
  int gbase = (b << 12) + seg * SEGLEN;
  for (int ch = 0; ch < SEGLEN / 128; ++ch) {
    __syncthreads();
    if (threadIdx.x < 128) {
      const float* p = &vw[(size_t)(gbase + ch * 128 + threadIdx.x) * 3];
      float x = p[0], y = p[1], z = p[2];
      float4 v; v.x = x; v.y = y; v.z = z;
      v.w = fmaf(z, z, fmaf(y, y, x * x));
      sc[threadIdx.x] = v;
    }
    __syncthreads();
    int m0 = seg * SEGLEN + ch * 128;
    for (int j = 0; j < 128; ++j) {
      float4 c = sc[j];
      float dot = fmaf(qz, c.z, fmaf(qy, c.y, qx * c.x));
      float d = fmaxf(qn + c.w - 2.f * dot, 0.f);
      topk_ins<KNN>(dv, iv, d, m0 + j);
    }
  }
  float* pdq = pd + ((size_t)Q * NSEG + seg) * 16;
  int* piq = pi + ((size_t)Q * NSEG + seg) * 16;
#pragma unroll
  for (int s = 0; s < KNN; ++s) { pdq[s] = dv[s]; piq[s] = iv[s]; }
}

// ---------------- merge K=16 → final indices ----------------
__global__ __launch_bounds__(256) void k_merge16(
    const float* __restrict__ pd, const int* __restrict__ pi, int* __restrict__ oidx)
{
  int Q = blockIdx.x * 256 + threadIdx.x;
  float dv[KNN]; int iv[KNN];
#pragma unroll
  for (int s = 0; s < KNN; ++s) { dv[s] = 3.4e38f; iv[s] = 0; }
  for (int s = 0; s < NSEG; ++s) {
    const float* pdq = pd + ((size_t)Q * NSEG + s) * 16;
    const int* piq = pi + ((size_t)Q * NSEG + s) * 16;
#pragma unroll
    for (int j = 0; j < KNN; ++j) topk_ins<KNN>(dv, iv, pdq[j], piq[j]);
  }
#pragma unroll
  for (int j = 0; j < KNN; ++j) oidx[(size_t)Q * KNN + j] = iv[j];
}

// ---------------- fused cost-volume MLP + weightnet1 + k-sum ----------------
__global__ __launch_bounds__(256) void k_mlp(
    const float* __restrict__ p1t, const float* __restrict__ p2t,
    const float* __restrict__ x1t, const float* __restrict__ x2t,
    const int* __restrict__ kidx,
    const float* __restrict__ W1, const float* __restrict__ B1v,
    const float* __restrict__ W2, const float* __restrict__ B2v,
    const float* __restrict__ wnw1, const float* __restrict__ wnb1,
    const float* __restrict__ wnw2, const float* __restrict__ wnb2,
    const float* __restrict__ wnw3, const float* __restrict__ wnb3,
    float* __restrict__ ptp)
{
  __shared__ __align__(16) float s_p1[64];
  __shared__ __align__(16) float s_g2t[64][20];
  __shared__ __align__(16) float s_dirt[3][20];
  __shared__ __align__(16) float s_h1t[128][20];
  __shared__ __align__(16) float s_wn[16][8];
  __shared__ __align__(16) float s_red[2][128];
  int gid = blockIdx.x, b = gid >> 12, tid = threadIdx.x;
  int ch = tid & 127, kh = tid >> 7, kb = kh * 8;

  if (tid < 16) ((float4*)s_p1)[tid] = *(const float4*)&p1t[(size_t)gid * 64 + tid * 4];
  int k_ld = tid >> 4, c_ld = (tid & 15) * 4;
  int m = kidx[(size_t)gid * 16 + k_ld];
  int grow = (b << 12) + m;
  float4 gv = *(const float4*)&p2t[(size_t)grow * 64 + c_ld];
  s_g2t[c_ld + 0][k_ld] = gv.x;
  s_g2t[c_ld + 1][k_ld] = gv.y;
  s_g2t[c_ld + 2][k_ld] = gv.z;
  s_g2t[c_ld + 3][k_ld] = gv.w;
  if ((tid & 15) == 0) {
    float4 c2 = *(const float4*)&x2t[(size_t)grow * 4];
    float4 c1 = *(const float4*)&x1t[(size_t)gid * 4];
    s_dirt[0][k_ld] = c2.x - c1.x;
    s_dirt[1][k_ld] = c2.y - c1.y;
    s_dirt[2][k_ld] = c2.z - c1.z;
  }
  __syncthreads();
  if (tid < 16) {
    float dx = s_dirt[0][tid], dy = s_dirt[1][tid], dz = s_dirt[2][tid];
    float h1w[8];
#pragma unroll
    for (int j = 0; j < 8; ++j)
      h1w[j] = fmaxf(fmaf(dz, wnw1[16 + j], fmaf(dy, wnw1[8 + j], fmaf(dx, wnw1[j], wnb1[j]))), 0.f);
#pragma unroll
    for (int j = 0; j < 8; ++j) {
      float a = wnb2[j];
#pragma unroll
      for (int qq = 0; qq < 8; ++qq) a = fmaf(h1w[qq], wnw2[qq * 8 + j], a);
      s_wn[tid][j] = fmaxf(a, 0.f);
    }
  }
  // layer1 p1-center part (same for all k)
  float pre = B1v[ch];
#pragma unroll
  for (int c4 = 0; c4 < 16; ++c4) {
    float4 p = ((float4*)s_p1)[c4];
    const float* wr = &W1[(size_t)c4 * 4 * 128 + ch];
    pre = fmaf(p.x, wr[0], pre);
    pre = fmaf(p.y, wr[128], pre);
    pre = fmaf(p.z, wr[256], pre);
    pre = fmaf(p.w, wr[384], pre);
  }
  float acc[8];
#pragma unroll
  for (int j = 0; j < 8; ++j) acc[j] = pre;
  for (int c = 0; c < 64; ++c) {
    float4 g0 = *(const float4*)&s_g2t[c][kb];
    float4 g1 = *(const float4*)&s_g2t[c][kb + 4];
    float w = W1[(size_t)(64 + c) * 128 + ch];
    acc[0] = fmaf(g0.x, w, acc[0]); acc[1] = fmaf(g0.y, w, acc[1]);
    acc[2] = fmaf(g0.z, w, acc[2]); acc[3] = fmaf(g0.w, w, acc[3]);
    acc[4] = fmaf(g1.x, w, acc[4]); acc[5] = fmaf(g1.y, w, acc[5]);
    acc[6] = fmaf(g1.z, w, acc[6]); acc[7] = fmaf(g1.w, w, acc[7]);
  }
#pragma unroll
  for (int jd = 0; jd < 3; ++jd) {
    float4 d0 = *(const float4*)&s_dirt[jd][kb];
    float4 d1 = *(const float4*)&s_dirt[jd][kb + 4];
    float w = W1[(size_t)(128 + jd) * 128 + ch];
    acc[0] = fmaf(d0.x, w, acc[0]); acc[1] = fmaf(d0.y, w, acc[1]);
    acc[2] = fmaf(d0.z, w, acc[2]); acc[3] = fmaf(d0.w, w, acc[3]);
    acc[4] = fmaf(d1.x, w, acc[4]); acc[5] = fmaf(d1.y, w, acc[5]);
    acc[6] = fmaf(d1.z, w, acc[6]); acc[7] = fmaf(d1.w, w, acc[7]);
  }
#pragma unroll
  for (int j = 0; j < 8; ++j) s_h1t[ch][kb + j] = leakyf(acc[j]);
  __syncthreads();
  float acc2[8];
  float b2 = B2v[ch];
#pragma unroll
  for (int j = 0; j < 8; ++j) acc2[j] = b2;
  for (int c = 0; c < 128; ++c) {
    float4 h0 = *(const float4*)&s_h1t[c][kb];
    float4 h1 = *(const float4*)&s_h1t[c][kb + 4];
    float w = W2[(size_t)c * 128 + ch];
    acc2[0] = fmaf(h0.x, w, acc2[0]); acc2[1] = fmaf(h0.y, w, acc2[1]);
    acc2[2] = fmaf(h0.z, w, acc2[2]); acc2[3] = fmaf(h0.w, w, acc2[3]);
    acc2[4] = fmaf(h1.x, w, acc2[4]); acc2[5] = fmaf(h1.y, w, acc2[5]);
    acc2[6] = fmaf(h1.z, w, acc2[6]); acc2[7] = fmaf(h1.w, w, acc2[7]);
  }
  float r = 0.f;
#pragma unroll
  for (int j = 0; j < 8; ++j) {
    float v = leakyf(acc2[j]);
    int k = kb + j;
    float4 wa = *(const float4*)&s_wn[k][0];
    float4 wb = *(const float4*)&s_wn[k][4];
    float wv = wnb3[ch];
    wv = fmaf(wa.x, wnw3[ch], wv);
    wv = fmaf(wa.y, wnw3[128 + ch], wv);
    wv = fmaf(wa.z, wnw3[256 + ch], wv);
    wv = fmaf(wa.w, wnw3[384 + ch], wv);
    wv = fmaf(wb.x, wnw3[512 + ch], wv);
    wv = fmaf(wb.y, wnw3[640 + ch], wv);
    wv = fmaf(wb.z, wnw3[768 + ch], wv);
    wv = fmaf(wb.w, wnw3[896 + ch], wv);
    wv = fmaxf(wv, 0.f);
    r = fmaf(wv, v, r);
  }
  s_red[kh][ch] = r;
  __syncthreads();
  if (tid < 128) ptp[(size_t)gid * 128 + tid] = s_red[0][tid] + s_red[1][tid];
}

// ---------------- final: weightnet2 + gather + k-sum + transpose store ----------------
__global__ __launch_bounds__(256) void k_final(
    const float* __restrict__ x1t, const int* __restrict__ idx2,
    const float* __restrict__ ptp,
    const float* __restrict__ wnw1, const float* __restrict__ wnb1,
    const float* __restrict__ wnw2, const float* __restrict__ wnb2,
    const float* __restrict__ wnw3, const float* __restrict__ wnb3,
    float* __restrict__ out0)
{
  __shared__ __align__(16) float s_gc[16][128];
  __shared__ __align__(16) float s_wn[16][8];
  __shared__ __align__(16) float s_red[2][128];
  int gid = blockIdx.x, b = gid >> 12, n = gid & (NPTS - 1);
  int tid = threadIdx.x;
  if (tid < 16) {
    int m = idx2[(size_t)gid * 16 + tid];
    float4 c2 = *(const float4*)&x1t[(size_t)((b << 12) + m) * 4];
    float4 c1 = *(const float4*)&x1t[(size_t)gid * 4];
    float dx = c2.x - c1.x, dy = c2.y - c1.y, dz = c2.z - c1.z;
    float h1w[8];
#pragma unroll
    for (int j = 0; j < 8; ++j)
      h1w[j] = fmaxf(fmaf(dz, wnw1[16 + j], fmaf(dy, wnw1[8 + j], fmaf(dx, wnw1[j], wnb1[j]))), 0.f);
#pragma unroll
    for (int j = 0; j < 8; ++j) {
      float a = wnb2[j];
#pragma unroll
      for (int qq = 0; qq < 8; ++qq) a = fmaf(h1w[qq], wnw2[qq * 8 + j], a);
      s_wn[tid][j] = fmaxf(a, 0.f);
    }
  }
  int k2 = tid >> 4, i2 = tid & 15;
  int mg = idx2[(size_t)gid * 16 + k2];
  const float* src = &ptp[(size_t)((b << 12) + mg) * 128 + i2 * 8];
  *(float4*)&s_gc[k2][i2 * 8] = *(const float4*)&src[0];
  *(float4*)&s_gc[k2][i2 * 8 + 4] = *(const float4*)&src[4];
  __syncthreads();
  int ch = tid & 127, kg2 = tid >> 7;
  float r = 0.f;
#pragma unroll
  for (int jj = 0; jj < 8; ++jj) {
    int k = kg2 * 8 + jj;
    float4 wa = *(const float4*)&s_wn[k][0];
    float4 wb = *(const float4*)&s_wn[k][4];
    float wv = wnb3[ch];
    wv = fmaf(wa.x, wnw3[ch], wv);
    wv = fmaf(wa.y, wnw3[128 + ch], wv);
    wv = fmaf(wa.z, wnw3[256 + ch], wv);
    wv = fmaf(wa.w, wnw3[384 + ch], wv);
    wv = fmaf(wb.x, wnw3[512 + ch], wv);
    wv = fmaf(wb.y, wnw3[640 + ch], wv);
    wv = fmaf(wb.z, wnw3[768 + ch], wv);
    wv = fmaf(wb.w, wnw3[896 + ch], wv);
    wv = fmaxf(wv, 0.f);
    r = fmaf(wv, s_gc[k][ch], r);
  }
  s_red[kg2][ch] = r;
  __syncthreads();
  if (tid < 128)
    out0[(size_t)(b * 128 + tid) * NPTS + n] = s_red[0][tid] + s_red[1][tid];
}

extern "C" void kernel_launch(void* const* d_in, const int* in_sizes, int n_in,
                              void* d_out, int out_size, void* d_ws, size_t ws_size,
                              hipStream_t stream) {
  (void)in_sizes; (void)n_in; (void)out_size; (void)ws_size;
  const float* xyz1   = (const float*)d_in[0];
  const float* xyz2   = (const float*)d_in[1];
  const float* pts1   = (const float*)d_in[2];
  const float* pts2   = (const float*)d_in[3];
  const float* vel1   = (const float*)d_in[4];
  const float* w_xyz  = (const float*)d_in[8];
  const float* w_pts  = (const float*)d_in[10];
  const float* mlp_w1 = (const float*)d_in[11];
  const float* mlp_b1 = (const float*)d_in[12];
  const float* mlp_w2 = (const float*)d_in[13];
  const float* mlp_b2 = (const float*)d_in[14];
  const float* wn1_w1 = (const float*)d_in[15];
  const float* wn1_b1 = (const float*)d_in[16];
  const float* wn1_w2 = (const float*)d_in[17];
  const float* wn1_b2 = (const float*)d_in[18];
  const float* wn1_w3 = (const float*)d_in[19];
  const float* wn1_b3 = (const float*)d_in[20];
  const float* wn2_w1 = (const float*)d_in[21];
  const float* wn2_b1 = (const float*)d_in[22];
  const float* wn2_w2 = (const float*)d_in[23];
  const float* wn2_b2 = (const float*)d_in[24];
  const float* wn2_w3 = (const float*)d_in[25];
  const float* wn2_b3 = (const float*)d_in[26];

  char* ws = (char*)d_ws;
  size_t off = 0;
  float* pd   = (float*)(ws + off); off += (size_t)NQ * NSEG * 16 * 4;   // 8 MB
  int*   pi   = (int*)(ws + off);   off += (size_t)NQ * NSEG * 16 * 4;   // 8 MB
  float* f1   = (float*)(ws + off); off += (size_t)NQ * FPAD * 4;
  float* f2   = (float*)(ws + off); off += (size_t)NQ * FPAD * 4;
  float* n1   = (float*)(ws + off); off += (size_t)NQ * 4;
  float* n2   = (float*)(ws + off); off += (size_t)NQ * 4;
  float* p1t  = (float*)(ws + off); off += (size_t)NQ * DD * 4;
  float* p2t  = (float*)(ws + off); off += (size_t)NQ * DD * 4;
  float* x1t  = (float*)(ws + off); off += (size_t)NQ * 4 * 4;
  float* x2t  = (float*)(ws + off); off += (size_t)NQ * 4 * 4;
  int*   kidx = (int*)(ws + off);   off += (size_t)NQ * KNN * 4;
  float* ptp  = (float*)(ws + off); off += (size_t)NQ * 128 * 4;
  int*   idx2 = (int*)(ws + off);   off += (size_t)NQ * KNN * 4;

  float* out0 = (float*)d_out;
  float* outv = (float*)d_out + VOFF;

  k_prep<<<32, 256, 0, stream>>>(xyz1, xyz2, pts1, pts2, w_xyz, w_pts,
                                 f1, f2, n1, n2, p1t, p2t, x1t, x2t);
  k_knn3<<<dim3(32, NSEG), 256, 0, stream>>>(x1t, pd, pi);
  k_rigid<<<32, 256, 0, stream>>>(pd, pi, x1t, vel1, outv);
  k_knnf<<<dim3(32, NSEG), 256, 0, stream>>>(f1, f2, n1, n2, pd, pi);
  k_merge16<<<32, 256, 0, stream>>>(pd, pi, kidx);
  k_mlp<<<NQ, 256, 0, stream>>>(p1t, p2t, x1t, x2t, kidx,
                                mlp_w1, mlp_b1, mlp_w2, mlp_b2,
                                wn1_w1, wn1_b1, wn1_w2, wn1_b2, wn1_w3, wn1_b3, ptp);
  k_knnv<<<dim3(32, NSEG), 256, 0, stream>>>(outv, pd, pi);
  k_merge16<<<32, 256, 0, stream>>>(pd, pi, idx2);
  k_final<<<NQ, 256, 0, stream>>>(x1t, idx2, ptp,
                                  wn2_w1, wn2_b1, wn2_w2, wn2_b2, wn2_w3, wn2_b3, out0);
}